// Round 10
// baseline (183.486 us; speedup 1.0000x reference)
//
#include <hip/hip_runtime.h>
#include <hip/hip_cooperative_groups.h>

namespace cg = cooperative_groups;

#define S_DIM 256
#define B_DIM 64
#define IN_DIM 3
#define H_DIM 128
#define N_NODES 1000000
#define NM1 (N_NODES - 1)
#define N4_TOTAL (N_NODES / 4)
#define P_INF 8
#define P_OUTF 32
#define NUM_GRAPHS 64
#define EPSF 1e-6f

// d_out float offsets
#define OUT_OUTPUTS 0
#define OUT_HIDDEN (S_DIM * B_DIM * H_DIM)            // 2097152
#define OUT_LG (OUT_HIDDEN + B_DIM * H_DIM)           // 2105344

#define TPB 512
#define NBLK_MAX 1024
#define SG_SLOTS 6

// ws float offsets
#define WS_HIDPART 0                                   // 16 * 64 * 128 floats
#define WS_TBLV (16 * B_DIM * H_DIM)                   // + NBLK_MAX*SG_SLOTS floats
#define WS_TBLG (WS_TBLV + NBLK_MAX * SG_SLOTS)        // + NBLK_MAX ints

typedef float f4v __attribute__((ext_vector_type(4)));
typedef int i4v __attribute__((ext_vector_type(4)));

// ---------------------------------------------------------------------------
// Single cooperative kernel.
// Phase A: fc_in (blocks 0..255) + lg scores + block-local masked exp-sums
//          into a no-init partial table. Streaming reads are nontemporal.
// grid.sync()
// Phase B: blocks covering n4<250k reduce the partial table into LDS gsum[64]
//          and transform lg in-place; last 64 blocks do the fusion MLP.
// No max subtraction: lg is O(3); eps-shift error ~1e-9 << threshold.
// __launch_bounds__(512, 8) forces VGPR<=64 -> 4 blocks/CU -> 1024 blocks
// co-resident (verified at launch via the occupancy API; grid-strided phases
// keep correctness for any nblk).
// ---------------------------------------------------------------------------
__global__ void __launch_bounds__(TPB, 8)
fused_kernel(const float* __restrict__ src, const int* __restrict__ src_len,
             const float* __restrict__ W_in, const float* __restrict__ b_in,
             const float* __restrict__ node_x, const float* __restrict__ W_pred,
             const float* __restrict__ b_pred, const float* __restrict__ node_w,
             const int* __restrict__ gids,
             const float* __restrict__ pro, const float* __restrict__ W_extra,
             const float* __restrict__ b_extra, const float* __restrict__ W_hid,
             const float* __restrict__ b_hid,
             float* __restrict__ outputs, float* __restrict__ hidden_out,
             float* __restrict__ lg, float* __restrict__ hid_partial,
             float* __restrict__ tblV, int* __restrict__ tblG, int rpb) {
    __shared__ float sg[SG_SLOTS];
    __shared__ float gsum[NUM_GRAPHS];
    __shared__ float sh[P_OUTF + H_DIM];
    const int tid = threadIdx.x;
    const int blk = blockIdx.x;
    const int nblk = gridDim.x;
    if (tid < SG_SLOTS) sg[tid] = 0.0f;

    // ================= Phase A =================
    if (blk < 256) {
        int b = blk & 63;
        int chunk = blk >> 6;          // 0..3 (64 s each)
        int h = tid & 127;
        int sq = tid >> 7;             // 0..3 (16 s each)
        float w0 = W_in[h], w1 = W_in[H_DIM + h], w2 = W_in[2 * H_DIM + h];
        float bi = b_in[h];
        int len = src_len[b];
        float facc = 0.0f;
        int s0 = chunk * 64 + sq * 16;
        for (int s = s0; s < s0 + 16; ++s) {
            const float* sp = src + ((size_t)s * B_DIM + b) * IN_DIM;
            float v = fmaf(sp[0], w0, fmaf(sp[1], w1, fmaf(sp[2], w2, bi)));
            v = (s < len) ? v : 0.0f;
            outputs[((size_t)s * B_DIM + b) * H_DIM + h] = v;
            facc += v;
        }
        hid_partial[((size_t)(chunk * 4 + sq) * B_DIM + b) * H_DIM + h] = facc;
    }
    __syncthreads();   // sg zeroed & visible

    const int start = blk * rpb;
    const int bend = min(start + rpb, N_NODES);
    const int gfirst = gids[min(start, NM1)];
    const int w = tid >> 6;        // wave 0..7
    const int lane = tid & 63;
    const int p = lane & 7;        // piece within row
    const int rloc = lane >> 3;    // row within the 8-row group

    f4v wch0 = ((const f4v*)W_pred)[p];
    f4v wch1 = ((const f4v*)W_pred)[p + 8];
    f4v wch2 = ((const f4v*)W_pred)[p + 16];
    f4v wch3 = ((const f4v*)W_pred)[p + 24];
    const float bp = b_pred[0];

    int curg = -1;
    float acc = 0.0f;

    for (int r0 = start + w * 8; r0 < bend; r0 += 64) {
        int sidx = min(r0 + p, NM1);
        float wv = node_w[sidx];
        int gv = gids[sidx];
        int xrow = min(r0 + rloc, NM1);
        const f4v* xb = (const f4v*)(node_x + (size_t)xrow * H_DIM);
        f4v x0 = __builtin_nontemporal_load(xb + p);
        f4v x1 = __builtin_nontemporal_load(xb + p + 8);
        f4v x2 = __builtin_nontemporal_load(xb + p + 16);
        f4v x3 = __builtin_nontemporal_load(xb + p + 24);
        float s = x0.x * wch0.x + x0.y * wch0.y + x0.z * wch0.z + x0.w * wch0.w;
        s += x1.x * wch1.x + x1.y * wch1.y + x1.z * wch1.z + x1.w * wch1.w;
        s += x2.x * wch2.x + x2.y * wch2.y + x2.z * wch2.z + x2.w * wch2.w;
        s += x3.x * wch3.x + x3.y * wch3.y + x3.z * wch3.z + x3.w * wch3.w;
        s += __shfl_xor(s, 1);
        s += __shfl_xor(s, 2);
        s += __shfl_xor(s, 4);
        float rowsum = __shfl(s, p * 8);   // lane j gets row j's sum
        int myrow = r0 + p;
        if (lane < 8 && myrow < bend) {
            float score = rowsum + bp;
            __builtin_nontemporal_store(score, &lg[myrow]);
            float xe = __expf(score) * wv;
            if (gv != curg) {
                if (curg >= 0) atomicAdd(&sg[min(curg - gfirst, SG_SLOTS - 1)], acc);
                curg = gv;
                acc = 0.0f;
            }
            acc += xe;
        }
    }
    if (curg >= 0) atomicAdd(&sg[min(curg - gfirst, SG_SLOTS - 1)], acc);
    __syncthreads();
    if (tid < SG_SLOTS) tblV[blk * SG_SLOTS + tid] = sg[tid];
    if (tid == 0) tblG[blk] = gfirst;

    // ================= grid barrier =================
    cg::this_grid().sync();

    // ================= Phase B =================
    if (blk >= nblk - 64) {
        // ---- fusion duty (last 64 blocks) ----
        int b = blk - (nblk - 64);
        if (tid < P_OUTF) {
            float a = b_extra[tid];
            #pragma unroll
            for (int k = 0; k < P_INF; ++k) a += pro[b * P_INF + k] * W_extra[k * P_OUTF + tid];
            sh[tid] = tanhf(a);
        }
        if (tid < H_DIM) {
            float m = 0.0f;
            #pragma unroll
            for (int c = 0; c < 16; ++c) m += hid_partial[((size_t)c * B_DIM + b) * H_DIM + tid];
            sh[P_OUTF + tid] = m * (1.0f / S_DIM);
        }
        __syncthreads();
        if (tid < H_DIM) {
            float a = b_hid[tid];
            #pragma unroll 8
            for (int k = 0; k < P_OUTF + H_DIM; ++k) a += sh[k] * W_hid[k * H_DIM + tid];
            hidden_out[(size_t)b * H_DIM + tid] = tanhf(a);
        }
        return;
    }

    if (blk * TPB >= N4_TOTAL) return;   // idle blocks

    // ---- reduce partial table (L2-hot) into LDS gsum ----
    if (tid < NUM_GRAPHS) gsum[tid] = 0.0f;
    __syncthreads();
    for (int b = tid; b < nblk; b += TPB) {
        int gf = tblG[b];
        #pragma unroll
        for (int slot = 0; slot < SG_SLOTS; ++slot) {
            float v = tblV[b * SG_SLOTS + slot];
            if (v != 0.0f) atomicAdd(&gsum[min(gf + slot, NUM_GRAPHS - 1)], v);
        }
    }
    __syncthreads();

    // ---- lg_out slice ----
    int stride = (nblk - 64) * TPB;
    for (int n4 = blk * TPB + tid; n4 < N4_TOTAL; n4 += stride) {
        f4v l = __builtin_nontemporal_load((const f4v*)lg + n4);
        f4v wq = __builtin_nontemporal_load((const f4v*)node_w + n4);
        i4v g = __builtin_nontemporal_load((const i4v*)gids + n4);
        f4v r;
        r.x = __logf(fminf(fmaxf(__expf(l.x) * wq.x / (gsum[g.x] + EPSF), EPSF), 1.0f));
        r.y = __logf(fminf(fmaxf(__expf(l.y) * wq.y / (gsum[g.y] + EPSF), EPSF), 1.0f));
        r.z = __logf(fminf(fmaxf(__expf(l.z) * wq.z / (gsum[g.z] + EPSF), EPSF), 1.0f));
        r.w = __logf(fminf(fmaxf(__expf(l.w) * wq.w / (gsum[g.w] + EPSF), EPSF), 1.0f));
        __builtin_nontemporal_store(r, (f4v*)lg + n4);
    }
}

extern "C" void kernel_launch(void* const* d_in, const int* in_sizes, int n_in,
                              void* d_out, int out_size, void* d_ws, size_t ws_size,
                              hipStream_t stream) {
    const float* src      = (const float*)d_in[0];
    const int*   src_len  = (const int*)d_in[1];
    const float* node_x   = (const float*)d_in[2];
    const float* node_w   = (const float*)d_in[3];
    const int*   gids     = (const int*)d_in[4];
    const float* pro      = (const float*)d_in[5];
    const float* W_in     = (const float*)d_in[6];
    const float* b_in     = (const float*)d_in[7];
    const float* W_pred   = (const float*)d_in[8];
    const float* b_pred   = (const float*)d_in[9];
    const float* W_extra  = (const float*)d_in[10];
    const float* b_extra  = (const float*)d_in[11];
    const float* W_hid    = (const float*)d_in[12];
    const float* b_hid    = (const float*)d_in[13];

    float* out = (float*)d_out;
    float* outputs = out + OUT_OUTPUTS;
    float* hidden  = out + OUT_HIDDEN;
    float* lg      = out + OUT_LG;     // scratch for scores, overwritten in-place

    float* ws = (float*)d_ws;
    float* hid_partial = ws + WS_HIDPART;
    float* tblV = ws + WS_TBLV;
    int*   tblG = (int*)(ws + WS_TBLG);

    // co-residency check (host-only query; deterministic)
    int nb_per_cu = 0;
    hipOccupancyMaxActiveBlocksPerMultiprocessor(&nb_per_cu, (const void*)fused_kernel,
                                                 TPB, 0);
    int nblk = nb_per_cu * 256;
    if (nblk > NBLK_MAX) nblk = NBLK_MAX;
    if (nblk < 320) nblk = 320;        // floor: fc_in needs 256, fusion needs 64
    int rpb = (N_NODES + nblk - 1) / nblk;

    void* args[] = {
        (void*)&src, (void*)&src_len, (void*)&W_in, (void*)&b_in,
        (void*)&node_x, (void*)&W_pred, (void*)&b_pred, (void*)&node_w,
        (void*)&gids, (void*)&pro, (void*)&W_extra, (void*)&b_extra,
        (void*)&W_hid, (void*)&b_hid,
        (void*)&outputs, (void*)&hidden, (void*)&lg, (void*)&hid_partial,
        (void*)&tblV, (void*)&tblG, (void*)&rpb
    };
    hipLaunchCooperativeKernel((const void*)fused_kernel, dim3(nblk), dim3(TPB),
                               args, 0, stream);
}

// Round 11
// 123.386 us; speedup vs baseline: 1.4871x; 1.4871x over previous
//
#include <hip/hip_runtime.h>

#define S_DIM 256
#define B_DIM 64
#define IN_DIM 3
#define H_DIM 128
#define N_NODES 1000000
#define NM1 (N_NODES - 1)
#define P_INF 8
#define P_OUTF 32
#define NUM_GRAPHS 64
#define EPSF 1e-6f
#define LOG_EPSF -13.815510558f   // logf(1e-6)
#define NEG_BIG -1e30f

// d_out float offsets
#define OUT_OUTPUTS 0
#define OUT_HIDDEN (S_DIM * B_DIM * H_DIM)            // 2097152
#define OUT_LG (OUT_HIDDEN + B_DIM * H_DIM)           // 2105344

// main kernel geometry: 1024 blocks x 512 threads (8 waves). Each block owns
// a contiguous 977-row range; its 8 waves interleave 8-row groups round-robin
// (block read front advances 32 KB/round -> 1024 long streams).
#define NBLK 1024
#define TPB 512
#define RPB 977            // 1024*977 = 1,000,448 >= 1e6
#define GSTEP 64           // 8 waves x 8 rows
#define SG_SLOTS 6

// ws float offsets
#define WS_HIDPART 0                                   // 16 * 64 * 128 floats
#define WS_TBLV (16 * B_DIM * H_DIM)                   // + NBLK*SG_SLOTS floats
#define WS_TBLG (WS_TBLV + NBLK * SG_SLOTS)            // + NBLK ints

// ---------------------------------------------------------------------------
// K1 "main": lg scores + block-local masked exp-sums into a no-init partial
// table. Blocks 0..255 also do fc_in. Stored score encodes the mask:
// w==0 rows store -1e30 (finish pass then needs no node_w read).
// No max subtraction: lg is O(3); eps-shift error ~1e-9 << threshold.
// ---------------------------------------------------------------------------
__global__ void __launch_bounds__(TPB)
main_kernel(const float* __restrict__ src, const int* __restrict__ src_len,
            const float* __restrict__ W_in, const float* __restrict__ b_in,
            const float* __restrict__ node_x, const float* __restrict__ W_pred,
            const float* __restrict__ b_pred, const float* __restrict__ node_w,
            const int* __restrict__ gids,
            float* __restrict__ outputs, float* __restrict__ hid_partial,
            float* __restrict__ lg, float* __restrict__ tblV, int* __restrict__ tblG) {
    __shared__ float sg[SG_SLOTS];
    const int tid = threadIdx.x;
    const int blk = blockIdx.x;
    if (tid < SG_SLOTS) sg[tid] = 0.0f;

    // ---- fc_in duty (blocks 0..255, all 512 threads) ----
    if (blk < 256) {
        int b = blk & 63;
        int chunk = blk >> 6;          // 0..3 (64 s each)
        int h = tid & 127;
        int sq = tid >> 7;             // 0..3 (16 s each)
        float w0 = W_in[h], w1 = W_in[H_DIM + h], w2 = W_in[2 * H_DIM + h];
        float bi = b_in[h];
        int len = src_len[b];
        float facc = 0.0f;
        int s0 = chunk * 64 + sq * 16;
        for (int s = s0; s < s0 + 16; ++s) {
            const float* sp = src + ((size_t)s * B_DIM + b) * IN_DIM;
            float v = fmaf(sp[0], w0, fmaf(sp[1], w1, fmaf(sp[2], w2, bi)));
            v = (s < len) ? v : 0.0f;
            outputs[((size_t)s * B_DIM + b) * H_DIM + h] = v;
            facc += v;
        }
        hid_partial[((size_t)(chunk * 4 + sq) * B_DIM + b) * H_DIM + h] = facc;
    }
    __syncthreads();   // sg zeroed & visible

    // ---- lg + exp-sum duty ----
    const int start = blk * RPB;
    const int bend = min(start + RPB, N_NODES);
    const int gfirst = gids[min(start, NM1)];
    const int w = tid >> 6;        // wave 0..7
    const int lane = tid & 63;
    const int p = lane & 7;        // piece within row
    const int rloc = lane >> 3;    // row within the 8-row group

    float4 wch0 = ((const float4*)W_pred)[p];
    float4 wch1 = ((const float4*)W_pred)[p + 8];
    float4 wch2 = ((const float4*)W_pred)[p + 16];
    float4 wch3 = ((const float4*)W_pred)[p + 24];
    const float bp = b_pred[0];

    int curg = -1;
    float acc = 0.0f;

    for (int r0 = start + w * 8; r0 < bend; r0 += GSTEP) {
        // side data for rows r0..r0+7 (same cachelines for the whole wave)
        int sidx = min(r0 + p, NM1);
        float wv = node_w[sidx];
        int gv = gids[sidx];
        // main row data: 8 rows x 512B = 4KB per wave, contiguous
        int xrow = min(r0 + rloc, NM1);
        const float4* xb = (const float4*)(node_x + (size_t)xrow * H_DIM);
        float4 x0 = xb[p];
        float4 x1 = xb[p + 8];
        float4 x2 = xb[p + 16];
        float4 x3 = xb[p + 24];
        float s = x0.x * wch0.x + x0.y * wch0.y + x0.z * wch0.z + x0.w * wch0.w;
        s += x1.x * wch1.x + x1.y * wch1.y + x1.z * wch1.z + x1.w * wch1.w;
        s += x2.x * wch2.x + x2.y * wch2.y + x2.z * wch2.z + x2.w * wch2.w;
        s += x3.x * wch3.x + x3.y * wch3.y + x3.z * wch3.z + x3.w * wch3.w;
        s += __shfl_xor(s, 1);
        s += __shfl_xor(s, 2);
        s += __shfl_xor(s, 4);
        float rowsum = __shfl(s, p * 8);   // lane j gets row j's sum
        int myrow = r0 + p;
        if (lane < 8 && myrow < bend) {
            float score = rowsum + bp;
            // encode mask: finish pass needs no node_w
            lg[myrow] = (wv != 0.0f) ? score : NEG_BIG;
            float xe = __expf(score) * wv;
            if (gv != curg) {
                if (curg >= 0) atomicAdd(&sg[min(curg - gfirst, SG_SLOTS - 1)], acc);
                curg = gv;
                acc = 0.0f;
            }
            acc += xe;
        }
    }
    if (curg >= 0) atomicAdd(&sg[min(curg - gfirst, SG_SLOTS - 1)], acc);
    __syncthreads();
    if (tid < SG_SLOTS) tblV[blk * SG_SLOTS + tid] = sg[tid];
    if (tid == 0) tblG[blk] = gfirst;
}

// ---------------------------------------------------------------------------
// K2 "finish": blocks 0..976 reduce the partial table into LDS, precompute
// lsum[g] = log(gsum[g]+eps), then out = max(score - lsum[g], LOG_EPS)
// (log-form: pred<=1 is guaranteed since sum >= exp(lg)*w; w==0 rows carry
// score=-1e30 -> LOG_EPS). Blocks 977..1040 do fusion.
// ---------------------------------------------------------------------------
#define LGOUT_BLOCKS 977

__global__ void __launch_bounds__(256)
finish_kernel(const float* __restrict__ tblV, const int* __restrict__ tblG,
              float* __restrict__ lg, const int* __restrict__ gids,
              const float* __restrict__ pro, const float* __restrict__ W_extra,
              const float* __restrict__ b_extra, const float* __restrict__ W_hid,
              const float* __restrict__ b_hid, const float* __restrict__ hid_partial,
              float* __restrict__ hidden_out) {
    const int tid = threadIdx.x;
    const int blk = blockIdx.x;

    if (blk >= LGOUT_BLOCKS) {
        int b = blk - LGOUT_BLOCKS;
        __shared__ float sh[P_OUTF + H_DIM];
        if (tid < P_OUTF) {
            float a = b_extra[tid];
            #pragma unroll
            for (int k = 0; k < P_INF; ++k) a += pro[b * P_INF + k] * W_extra[k * P_OUTF + tid];
            sh[tid] = tanhf(a);
        }
        if (tid < H_DIM) {
            float m = 0.0f;
            #pragma unroll
            for (int c = 0; c < 16; ++c) m += hid_partial[((size_t)c * B_DIM + b) * H_DIM + tid];
            sh[P_OUTF + tid] = m * (1.0f / S_DIM);
        }
        __syncthreads();
        if (tid < H_DIM) {
            float a = b_hid[tid];
            #pragma unroll 8
            for (int k = 0; k < P_OUTF + H_DIM; ++k) a += sh[k] * W_hid[k * H_DIM + tid];
            hidden_out[(size_t)b * H_DIM + tid] = tanhf(a);
        }
        return;
    }

    __shared__ float gsum[NUM_GRAPHS];
    if (tid < NUM_GRAPHS) gsum[tid] = 0.0f;
    __syncthreads();
    {
        int cg2 = -1;
        float a = 0.0f;
        for (int b = tid * (NBLK / 256); b < (tid + 1) * (NBLK / 256); ++b) {  // 4 blocks/thread
            int gf = tblG[b];
            #pragma unroll
            for (int slot = 0; slot < SG_SLOTS; ++slot) {
                float v = tblV[b * SG_SLOTS + slot];
                if (v != 0.0f) {
                    int g = min(gf + slot, NUM_GRAPHS - 1);
                    if (g != cg2) {
                        if (cg2 >= 0) atomicAdd(&gsum[cg2], a);
                        cg2 = g;
                        a = 0.0f;
                    }
                    a += v;
                }
            }
        }
        if (cg2 >= 0) atomicAdd(&gsum[cg2], a);
    }
    __syncthreads();
    // per-graph log-denominator (64 logs per block, once)
    if (tid < NUM_GRAPHS) gsum[tid] = __logf(gsum[tid] + EPSF);
    __syncthreads();

    int n4 = blk * 256 + tid;
    if (n4 >= N_NODES / 4) return;
    float4 l = ((const float4*)lg)[n4];
    int4 g = ((const int4*)gids)[n4];
    float4 r;
    r.x = fmaxf(l.x - gsum[g.x], LOG_EPSF);
    r.y = fmaxf(l.y - gsum[g.y], LOG_EPSF);
    r.z = fmaxf(l.z - gsum[g.z], LOG_EPSF);
    r.w = fmaxf(l.w - gsum[g.w], LOG_EPSF);
    ((float4*)lg)[n4] = r;
}

extern "C" void kernel_launch(void* const* d_in, const int* in_sizes, int n_in,
                              void* d_out, int out_size, void* d_ws, size_t ws_size,
                              hipStream_t stream) {
    const float* src      = (const float*)d_in[0];
    const int*   src_len  = (const int*)d_in[1];
    const float* node_x   = (const float*)d_in[2];
    const float* node_w   = (const float*)d_in[3];
    const int*   gids     = (const int*)d_in[4];
    const float* pro      = (const float*)d_in[5];
    const float* W_in     = (const float*)d_in[6];
    const float* b_in     = (const float*)d_in[7];
    const float* W_pred   = (const float*)d_in[8];
    const float* b_pred   = (const float*)d_in[9];
    const float* W_extra  = (const float*)d_in[10];
    const float* b_extra  = (const float*)d_in[11];
    const float* W_hid    = (const float*)d_in[12];
    const float* b_hid    = (const float*)d_in[13];

    float* out = (float*)d_out;
    float* outputs = out + OUT_OUTPUTS;
    float* hidden  = out + OUT_HIDDEN;
    float* lg      = out + OUT_LG;     // scratch for scores, overwritten in-place

    float* ws = (float*)d_ws;
    float* hid_partial = ws + WS_HIDPART;
    float* tblV = ws + WS_TBLV;
    int*   tblG = (int*)(ws + WS_TBLG);

    main_kernel<<<NBLK, TPB, 0, stream>>>(src, src_len, W_in, b_in,
                                          node_x, W_pred, b_pred, node_w, gids,
                                          outputs, hid_partial, lg, tblV, tblG);

    finish_kernel<<<LGOUT_BLOCKS + B_DIM, 256, 0, stream>>>(tblV, tblG, lg, gids,
                                                            pro, W_extra, b_extra, W_hid,
                                                            b_hid, hid_partial, hidden);
}